// Round 1
// baseline (267.323 us; speedup 1.0000x reference)
//
#include <hip/hip_runtime.h>

// NCC loss, fused single pass.
// Layout [n][1][d][h][w], n=2, d=160, h=192, w=192, f32.
// Thread: 4 consecutive w at fixed h, streaming d over a 16-slice chunk.
//   H-window (5): direct global loads (L1-served reuse), shared across 5 channels
//   W-window (5): register sliding sums
//   D-window (5): 5-slot register ring, d-loop unrolled x5 => static ring indices
// Then cc = cross^2/(varI*varJ+eps) per voxel, block-reduced, atomicAdd to scalar.

namespace {
constexpr int Wd = 192, Hd = 192, Dd = 160;
constexpr int SH = 192;            // h stride
constexpr int SD = 192 * 192;      // d stride (36864)
constexpr long SN = (long)SD * 160; // n stride (5898240)
constexpr int CD = 16;             // d-chunk per block; T = CD+4 = 20, divisible by 5
constexpr float INV_V = 1.0f / 125.0f;
constexpr float EPSf = 1e-5f;

__device__ __forceinline__ void wslide(const float h[8], float o[4]) {
  // o[k] = sum(h[k..k+4]) via sliding update
  float s0 = h[0] + h[1] + h[2] + h[3] + h[4];
  float s1 = s0 - h[0] + h[5];
  float s2 = s1 - h[1] + h[6];
  float s3 = s2 - h[2] + h[7];
  o[0] = s0; o[1] = s1; o[2] = s2; o[3] = s3;
}
} // namespace

__global__ __launch_bounds__(256) void ncc_fused(const float* __restrict__ I,
                                                 const float* __restrict__ Jv,
                                                 float* __restrict__ out) {
  const int tid = threadIdx.x;
  const int tx = tid & 15;       // w-run index within 64-wide tile
  const int ty = tid >> 4;       // h row within 16-tall tile
  const int w0 = blockIdx.x * 64 + tx * 4;
  const int h  = blockIdx.y * 16 + ty;
  const int n  = blockIdx.z / 10;
  const int d_lo = (blockIdx.z % 10) * CD;

  const float* Ib = I  + (long)n * SN;
  const float* Jb = Jv + (long)n * SN;

  // cols needed: [w0-2, w0+6)
  const bool wfast = (w0 >= 2) && (w0 + 6 <= Wd);

  float ring[5][5][4];  // [phase][channel:{I,J,II,JJ,IJ}][k]
  float acc = 0.0f;

  constexpr int T = CD + 4; // 20 ring-fill steps; output d = d_lo + t - 4 for t>=4
  for (int t0 = 0; t0 < T; t0 += 5) {
    #pragma unroll
    for (int p = 0; p < 5; ++p) {           // phase = t % 5 = p (t0 multiple of 5)
      const int t = t0 + p;
      const int s = d_lo - 2 + t;           // slice whose 2D sums enter the ring

      float hsI[8], hsJ[8], hsII[8], hsJJ[8], hsIJ[8];
      #pragma unroll
      for (int c = 0; c < 8; ++c) {
        hsI[c] = 0.f; hsJ[c] = 0.f; hsII[c] = 0.f; hsJJ[c] = 0.f; hsIJ[c] = 0.f;
      }

      if (s >= 0 && s < Dd) {               // zero padding in D: skip loads, keep zeros
        const float* sI = Ib + (long)s * SD + (w0 - 2);
        const float* sJ = Jb + (long)s * SD + (w0 - 2);
        #pragma unroll
        for (int dh = -2; dh <= 2; ++dh) {
          const int hh = h + dh;
          if (hh >= 0 && hh < Hd) {         // zero padding in H
            const float* rI = sI + hh * SH;
            const float* rJ = sJ + hh * SH;
            float a[8], b[8];
            if (wfast) {
              __builtin_memcpy(a, rI, 32);  // 8 consecutive floats (unaligned ok)
              __builtin_memcpy(b, rJ, 32);
            } else {
              #pragma unroll
              for (int c = 0; c < 8; ++c) { // zero padding in W (edge runs only)
                const int w = w0 - 2 + c;
                const bool ok = (w >= 0) && (w < Wd);
                a[c] = ok ? rI[c] : 0.0f;
                b[c] = ok ? rJ[c] : 0.0f;
              }
            }
            #pragma unroll
            for (int c = 0; c < 8; ++c) {
              const float x = a[c], y = b[c];
              hsI[c]  += x;
              hsJ[c]  += y;
              hsII[c] = fmaf(x, x, hsII[c]);
              hsJJ[c] = fmaf(y, y, hsJJ[c]);
              hsIJ[c] = fmaf(x, y, hsIJ[c]);
            }
          }
        }
      }

      // W-direction 5-window over the 8 H-sums -> 4 outputs per channel
      wslide(hsI,  ring[p][0]);
      wslide(hsJ,  ring[p][1]);
      wslide(hsII, ring[p][2]);
      wslide(hsJJ, ring[p][3]);
      wslide(hsIJ, ring[p][4]);

      if (t >= 4) {                          // output slice d = s - 2 ready
        #pragma unroll
        for (int k = 0; k < 4; ++k) {
          float SI = 0.f, SJ = 0.f, SII = 0.f, SJJ = 0.f, SIJ = 0.f;
          #pragma unroll
          for (int q = 0; q < 5; ++q) {      // D-direction 5-window
            SI  += ring[q][0][k];
            SJ  += ring[q][1][k];
            SII += ring[q][2][k];
            SJJ += ring[q][3][k];
            SIJ += ring[q][4][k];
          }
          const float cross = SIJ - SI * SJ * INV_V;
          const float vI    = SII - SI * SI * INV_V;
          const float vJ    = SJJ - SJ * SJ * INV_V;
          acc += cross * cross / (vI * vJ + EPSf);
        }
      }
    }
  }

  // block reduction -> single atomic per block
  #pragma unroll
  for (int off = 32; off > 0; off >>= 1) acc += __shfl_xor(acc, off, 64);
  __shared__ float red[4];
  if ((tid & 63) == 0) red[tid >> 6] = acc;
  __syncthreads();
  if (tid == 0) {
    const float total = red[0] + red[1] + red[2] + red[3];
    atomicAdd(out, total * (-1.0f / 11796480.0f)); // -mean over 2*160*192*192
  }
}

extern "C" void kernel_launch(void* const* d_in, const int* in_sizes, int n_in,
                              void* d_out, int out_size, void* d_ws, size_t ws_size,
                              hipStream_t stream) {
  const float* I = (const float*)d_in[0];
  const float* J = (const float*)d_in[1];
  float* out = (float*)d_out;
  // d_out is poisoned before every timed launch; we accumulate into it.
  hipMemsetAsync(out, 0, sizeof(float), stream);
  dim3 grid(3, 12, 20); // W tiles (3x64) * H tiles (12x16) * (n=2 x 10 d-chunks of 16)
  ncc_fused<<<grid, 256, 0, stream>>>(I, J, out);
}

// Round 2
// 257.794 us; speedup vs baseline: 1.0370x; 1.0370x over previous
//
#include <hip/hip_runtime.h>

// NCC loss, fused single pass. Layout [n][1][d][h][w], n=2, d=160, h=192, w=192, f32.
// Thread: 4 consecutive w at fixed h, streaming d over a CD-slice chunk.
//   H-window (5): direct global loads (L1-served reuse), shared across 5 channels
//   W-window (5): register sliding sums
//   D-window (5): 5-slot register ring, d-loop unrolled x5 => static ring indices
// R2: CD 16->6 (1944 blocks, ~30 waves/CU offered) for latency hiding;
//     row loads as 3x aligned float4 (base w0-4 is 16B-aligned) instead of
//     8B-aligned memcpy -> fewer VMEM instructions.

namespace {
constexpr int Wd = 192, Hd = 192, Dd = 160;
constexpr int SH = 192;             // h stride
constexpr int SD = 192 * 192;       // d stride
constexpr long SN = (long)SD * Dd;  // n stride
constexpr int CD = 6;               // d outputs per chunk; T = CD+4 = 10 (div by 5)
constexpr int NCHUNK = 27;          // ceil(160/6)
constexpr float INV_V = 1.0f / 125.0f;
constexpr float EPSf = 1e-5f;

__device__ __forceinline__ void wslide(const float h[8], float o[4]) {
  float s0 = h[0] + h[1] + h[2] + h[3] + h[4];
  float s1 = s0 - h[0] + h[5];
  float s2 = s1 - h[1] + h[6];
  float s3 = s2 - h[2] + h[7];
  o[0] = s0; o[1] = s1; o[2] = s2; o[3] = s3;
}
} // namespace

__global__ __launch_bounds__(256) void ncc_fused(const float* __restrict__ I,
                                                 const float* __restrict__ Jv,
                                                 float* __restrict__ out) {
  const int tid = threadIdx.x;
  const int tx = tid & 15;        // w-run index within 64-wide tile
  const int ty = tid >> 4;        // h row within 16-tall tile
  const int w0 = blockIdx.x * 64 + tx * 4;
  const int h  = blockIdx.y * 16 + ty;
  const int n  = blockIdx.z / NCHUNK;
  const int d_lo = (blockIdx.z % NCHUNK) * CD;

  const float* Ib = I  + (long)n * SN;
  const float* Jb = Jv + (long)n * SN;

  // fast path loads cols [w0-4, w0+8) as 3 aligned float4; uses [w0-2, w0+6)
  const bool wfast = (w0 >= 4) && (w0 + 8 <= Wd);

  float ring[5][5][4];  // [phase][channel:{I,J,II,JJ,IJ}][k]
  float acc = 0.0f;

  constexpr int T = CD + 4; // ring-fill steps; output d = d_lo + t - 4 for t>=4
  for (int t0 = 0; t0 < T; t0 += 5) {
    #pragma unroll
    for (int p = 0; p < 5; ++p) {           // phase = t % 5 = p
      const int t = t0 + p;
      if (t >= T) break;                    // (T=10: never taken; keeps generality)
      const int s = d_lo - 2 + t;           // slice entering the ring

      float hsI[8], hsJ[8], hsII[8], hsJJ[8], hsIJ[8];
      #pragma unroll
      for (int c = 0; c < 8; ++c) {
        hsI[c] = 0.f; hsJ[c] = 0.f; hsII[c] = 0.f; hsJJ[c] = 0.f; hsIJ[c] = 0.f;
      }

      if (s >= 0 && s < Dd) {               // zero padding in D
        const float* sI = Ib + (long)s * SD;
        const float* sJ = Jb + (long)s * SD;
        #pragma unroll
        for (int dh = -2; dh <= 2; ++dh) {
          const int hh = h + dh;
          if (hh >= 0 && hh < Hd) {         // zero padding in H
            const float* rI = sI + hh * SH;
            const float* rJ = sJ + hh * SH;
            float a[12], b[12];
            if (wfast) {
              const float4* pI = (const float4*)(rI + (w0 - 4));
              const float4* pJ = (const float4*)(rJ + (w0 - 4));
              ((float4*)a)[0] = pI[0]; ((float4*)a)[1] = pI[1]; ((float4*)a)[2] = pI[2];
              ((float4*)b)[0] = pJ[0]; ((float4*)b)[1] = pJ[1]; ((float4*)b)[2] = pJ[2];
            } else {
              #pragma unroll
              for (int c = 0; c < 12; ++c) { // zero padding in W (edge runs only)
                const int w = w0 - 4 + c;
                const bool ok = (w >= 0) && (w < Wd);
                a[c] = ok ? rI[w] : 0.0f;
                b[c] = ok ? rJ[w] : 0.0f;
              }
            }
            #pragma unroll
            for (int c = 0; c < 8; ++c) {
              const float x = a[c + 2], y = b[c + 2];
              hsI[c]  += x;
              hsJ[c]  += y;
              hsII[c] = fmaf(x, x, hsII[c]);
              hsJJ[c] = fmaf(y, y, hsJJ[c]);
              hsIJ[c] = fmaf(x, y, hsIJ[c]);
            }
          }
        }
      }

      // W-direction 5-window over the 8 H-sums -> 4 outputs per channel
      wslide(hsI,  ring[p][0]);
      wslide(hsJ,  ring[p][1]);
      wslide(hsII, ring[p][2]);
      wslide(hsJJ, ring[p][3]);
      wslide(hsIJ, ring[p][4]);

      const int d = d_lo + t - 4;
      if (t >= 4 && d < Dd) {               // output slice ready (guard tail chunk)
        #pragma unroll
        for (int k = 0; k < 4; ++k) {
          float SI = 0.f, SJ = 0.f, SII = 0.f, SJJ = 0.f, SIJ = 0.f;
          #pragma unroll
          for (int q = 0; q < 5; ++q) {     // D-direction 5-window
            SI  += ring[q][0][k];
            SJ  += ring[q][1][k];
            SII += ring[q][2][k];
            SJJ += ring[q][3][k];
            SIJ += ring[q][4][k];
          }
          const float cross = SIJ - SI * SJ * INV_V;
          const float vI    = SII - SI * SI * INV_V;
          const float vJ    = SJJ - SJ * SJ * INV_V;
          acc += cross * cross / (vI * vJ + EPSf);
        }
      }
    }
  }

  // block reduction -> single atomic per block
  #pragma unroll
  for (int off = 32; off > 0; off >>= 1) acc += __shfl_xor(acc, off, 64);
  __shared__ float red[4];
  if ((tid & 63) == 0) red[tid >> 6] = acc;
  __syncthreads();
  if (tid == 0) {
    const float total = red[0] + red[1] + red[2] + red[3];
    atomicAdd(out, total * (-1.0f / 11796480.0f)); // -mean over 2*160*192*192
  }
}

extern "C" void kernel_launch(void* const* d_in, const int* in_sizes, int n_in,
                              void* d_out, int out_size, void* d_ws, size_t ws_size,
                              hipStream_t stream) {
  const float* I = (const float*)d_in[0];
  const float* J = (const float*)d_in[1];
  float* out = (float*)d_out;
  hipMemsetAsync(out, 0, sizeof(float), stream);
  dim3 grid(3, 12, 2 * NCHUNK); // W tiles * H tiles * (n x 27 d-chunks of 6)
  ncc_fused<<<grid, 256, 0, stream>>>(I, J, out);
}